// Round 3
// baseline (184.401 us; speedup 1.0000x reference)
//
#include <hip/hip_runtime.h>
#include <stdint.h>

typedef __attribute__((ext_vector_type(4))) float float4v;

#define D 4096
#define R 16
#define NW 192     // adapters
#define LB 1280    // lora rows
#define NBL 256
#define MAXB 32    // max bucket size (actual max ~16-17, binomial(1280,1/192))
#define NWAVE 16   // waves per block

// ---------------- fused: per-adapter A->h->B->y ----------------
// Round-2 post-mortem: dur invariant at 54us across NSPLIT=1/4 while no pipe
// >20% busy -> bound by A/B fetch (96MB f32, steady-state FETCH ~60MB/dispatch)
// at only 1.5 TB/s effective: fetch happens in short bursts (16 loads/wave)
// separated by compute phases with zero bytes in flight.
// This version keeps grid=192 (no A/B re-fetch duplication) and maximizes
// fetch duty cycle INSIDE the block:
//  - B tile (16 x dwordx4/lane) hoisted into registers BEFORE phase 1: B's
//    48MB fetch overlaps all of phase-1 compute instead of stalling after
//    the barrier.
//  - x rows double-buffered in two named register arrays (2-unrolled loop,
//    no runtime indexing -> no scratch): row i+1's 16 loads in flight while
//    row i's FMA+shuffle chain runs.
// VGPR ~180 (a=64, breg=64, xv 2x16) -> still 1 block/CU, which is all the
// grid provides anyway; latency hiding is explicit ILP, not TLP.
__global__ __launch_bounds__(1024) void fused_kernel(
    const float* __restrict__ x,
    const float* __restrict__ A,
    const float* __restrict__ B,
    const int* __restrict__ xids,
    const int* __restrict__ wids,
    float* __restrict__ ybuf,   // [NBL*4][D]
    float* __restrict__ out)    // [512][D]
{
    const int w = blockIdx.x;
    const int t = threadIdx.x;
    const int lane = t & 63;
    const int wave = t >> 6;

    __shared__ int list[MAXB];
    __shared__ int xidl[MAXB];
    __shared__ int cnt;
    __shared__ float hws[MAXB][NWAVE][17];  // +1 pad: stride 17 kills bank conflicts
    __shared__ float hl[MAXB][R];

    if (t == 0) cnt = 0;
    __syncthreads();
    for (int i = t; i < LB; i += 1024)
        if (wids[i] == w) { int q = atomicAdd(&cnt, 1); if (q < MAXB) list[q] = i; }
    __syncthreads();
    int n = cnt > MAXB ? MAXB : cnt;
    if (n == 0) return;
    if (t < n) xidl[t] = xids[list[t]];
    __syncthreads();

    // lane owns d = 256*wave + (lane>>2) + 16k (k=0..15), r = 4*(lane&3)+c.
    const int dof = 256 * wave + (lane >> 2);

#define PREFETCH_X(idx, xv)                                          \
    { const float* xr_ = x + (size_t)xidl[idx] * D + dof;            \
      _Pragma("unroll")                                              \
      for (int k = 0; k < 16; ++k) xv[k] = xr_[16 * k]; }

#define ROW_REDUCE(i, xv)                                            \
    { float h0 = 0.f, h1 = 0.f, h2 = 0.f, h3 = 0.f;                  \
      _Pragma("unroll")                                              \
      for (int k = 0; k < 16; ++k) {                                 \
          const float xd = xv[k];                                    \
          h0 += xd * a[k][0]; h1 += xd * a[k][1];                    \
          h2 += xd * a[k][2]; h3 += xd * a[k][3];                    \
      }                                                              \
      _Pragma("unroll")                                              \
      for (int off = 4; off <= 32; off <<= 1) {                      \
          h0 += __shfl_xor(h0, off, 64); h1 += __shfl_xor(h1, off, 64); \
          h2 += __shfl_xor(h2, off, 64); h3 += __shfl_xor(h3, off, 64); \
      }                                                              \
      if (lane < 4) {                                                \
          hws[i][wave][4 * lane + 0] = h0;                           \
          hws[i][wave][4 * lane + 1] = h1;                           \
          hws[i][wave][4 * lane + 2] = h2;                           \
          hws[i][wave][4 * lane + 3] = h3;                           \
      } }

    // ---- issue order: x row 0, then A, then B ----
    // First-row FMAs then wait at vmcnt(16) (B still in flight); B's fetch
    // overlaps all of phase 1 and is complete long before phase 2.
    float xva[16], xvb[16];
    PREFETCH_X(0, xva);

    const float4v* af = (const float4v*)(A + (size_t)w * D * R);
    float4v a[16];
    #pragma unroll
    for (int k = 0; k < 16; ++k) a[k] = af[1024 * wave + 64 * k + lane];

    const float* Bw = B + (size_t)w * R * D + 4 * t;
    float4v breg[R];
    #pragma unroll
    for (int r = 0; r < R; ++r) breg[r] = *(const float4v*)(Bw + (size_t)r * D);

    // ---- phase 1: h[i][r] = x[xid_i] . A, 2-deep x prefetch pipeline ----
    for (int i = 0; i < n; i += 2) {
        if (i + 1 < n) PREFETCH_X(i + 1, xvb);
        ROW_REDUCE(i, xva);
        if (i + 1 < n) {
            if (i + 2 < n) PREFETCH_X(i + 2, xva);
            ROW_REDUCE(i + 1, xvb);
        }
    }
    __syncthreads();
    for (int idx = t; idx < n * R; idx += 1024) {
        const int i = idx >> 4, r = idx & 15;
        float sacc = 0.f;
        #pragma unroll
        for (int j = 0; j < NWAVE; ++j) sacc += hws[i][j][r];
        hl[i][r] = sacc;
    }
    __syncthreads();

    // ---- phase 2: y = 2*h.B (B already in registers) ----
    for (int i = 0; i < n; ++i) {
        const int b = list[i];
        float4v acc = {0.f, 0.f, 0.f, 0.f};
        #pragma unroll
        for (int r = 0; r < R; ++r) {
            const float hr = hl[i][r];         // LDS broadcast
            acc[0] += hr * breg[r][0];
            acc[1] += hr * breg[r][1];
            acc[2] += hr * breg[r][2];
            acc[3] += hr * breg[r][3];
        }
        #pragma unroll
        for (int k = 0; k < 4; ++k) acc[k] *= 2.0f;

        if (b < NBL * 4) {
            *(float4v*)(ybuf + (size_t)b * D + 4 * t) = acc;        // unique writer
        } else {
            *(float4v*)(out + (size_t)(NBL + (b - NBL * 4)) * D + 4 * t) = acc;
        }
    }
#undef PREFETCH_X
#undef ROW_REDUCE
}

// ---------------- sum4: out[o] = ybuf[4o]+ybuf[4o+1]+ybuf[4o+2]+ybuf[4o+3] ---
__global__ __launch_bounds__(256) void sum4_kernel(
    const float* __restrict__ ybuf,
    float* __restrict__ out)
{
    const int o = blockIdx.x >> 2;            // 0..255
    const int q = blockIdx.x & 3;             // d-quarter
    const int col = q * 1024 + 4 * threadIdx.x;
    const float* y0 = ybuf + (size_t)(4 * o) * D + col;
    float4v v0 = *(const float4v*)(y0);
    float4v v1 = *(const float4v*)(y0 + D);
    float4v v2 = *(const float4v*)(y0 + 2 * D);
    float4v v3 = *(const float4v*)(y0 + 3 * D);
    float4v s;
    #pragma unroll
    for (int k = 0; k < 4; ++k) s[k] = (v0[k] + v1[k]) + (v2[k] + v3[k]);
    *(float4v*)(out + (size_t)o * D + col) = s;
}

extern "C" void kernel_launch(void* const* d_in, const int* in_sizes, int n_in,
                              void* d_out, int out_size, void* d_ws, size_t ws_size,
                              hipStream_t stream) {
    const float* x    = (const float*)d_in[0];
    const float* A    = (const float*)d_in[1];
    const float* B    = (const float*)d_in[2];
    const int*   xids = (const int*)d_in[3];
    const int*   wids = (const int*)d_in[4];
    float*       out  = (float*)d_out;

    float* ybuf = (float*)d_ws;   // [1024][4096] f32 = 16 MB

    hipLaunchKernelGGL(fused_kernel, dim3(NW), dim3(1024), 0, stream,
                       x, A, B, xids, wids, ybuf, out);
    hipLaunchKernelGGL(sum4_kernel, dim3(NBL * 4), dim3(256), 0, stream,
                       ybuf, out);
}

// Round 4
// 149.364 us; speedup vs baseline: 1.2346x; 1.2346x over previous
//
#include <hip/hip_runtime.h>
#include <stdint.h>

typedef __attribute__((ext_vector_type(4))) float float4v;

#define D 4096
#define R 16
#define NW 192     // adapters
#define LB 1280    // lora rows
#define NBL 256
#define MAXB 32    // max bucket size (actual max ~16-17, binomial(1280,1/192))
#define NWAVE 16   // waves per block

// ---------------- fused: per-adapter A->h->B->y ----------------
// Round-3 post-mortem: VGPR_Count=64 + WRITE_SIZE 20->71MB = the A+B+2x
// register plan spilled to scratch (1024-thr block caps VGPR at 128; compiler
// chose 64). This version keeps round-0's register budget shape (A in regs,
// B only in phase 2) and instead fixes the phase-1 x path:
//  - x row slice loaded COALESCED: 1 dwordx4/lane per wave (1KB/instr) into a
//    per-wave LDS slice, re-read as 16 broadcast scalars (conflict-free:
//    16 banks x 4-lane same-addr broadcast). Was: 16 gather instrs moving
//    64B each at L2 latency -- the per-row serial chain that TLP (round 1)
//    couldn't hide.
//  - 2-deep row pipeline via two named float4 regs (8 VGPR): row i+1's
//    global load in flight under row i's LDS/FMA/shuffle chain. No barriers:
//    each wave owns its xs slice.
//  - B loads issued before the hws __syncthreads: overlap B fetch with the
//    hl-combine; a[] is dead by then so the allocator reuses its registers.
// __launch_bounds__(1024,4): 16-wave block = 4 waves/SIMD min -> VGPR<=128
// allowed; est. ~100 live. WRITE_SIZE==20480KB in counters is the no-spill
// check.
__global__ __launch_bounds__(1024, 4) void fused_kernel(
    const float* __restrict__ x,
    const float* __restrict__ A,
    const float* __restrict__ B,
    const int* __restrict__ xids,
    const int* __restrict__ wids,
    float* __restrict__ ybuf,   // [NBL*4][D]
    float* __restrict__ out)    // [512][D]
{
    const int w = blockIdx.x;
    const int t = threadIdx.x;
    const int lane = t & 63;
    const int wave = t >> 6;

    __shared__ int list[MAXB];
    __shared__ int xidl[MAXB];
    __shared__ int cnt;
    __shared__ float hws[MAXB][NWAVE][17];  // +1 pad: stride 17 kills bank conflicts
    __shared__ float hl[MAXB][R];
    __shared__ float xs[2][NWAVE][256];     // double-buffered per-wave x slices

    if (t == 0) cnt = 0;
    __syncthreads();
    for (int i = t; i < LB; i += 1024)
        if (wids[i] == w) { int q = atomicAdd(&cnt, 1); if (q < MAXB) list[q] = i; }
    __syncthreads();
    int n = cnt > MAXB ? MAXB : cnt;
    if (n == 0) return;
    if (t < n) xidl[t] = xids[list[t]];
    __syncthreads();

    // lane owns d = 256*wave + (lane>>2) + 16k (k=0..15), r = 4*(lane&3)+c.
    const int xcol = 256 * wave + 4 * lane;   // coalesced slice col for staging

    // issue row-0 x load first so it's in flight under the A burst
    float4v xv0 = *(const float4v*)(x + (size_t)xidl[0] * D + xcol);

    const float4v* af = (const float4v*)(A + (size_t)w * D * R);
    float4v a[16];
    #pragma unroll
    for (int k = 0; k < 16; ++k) a[k] = af[1024 * wave + 64 * k + lane];

#define ROW_COMPUTE(i, buf)                                               \
    { float h0 = 0.f, h1 = 0.f, h2 = 0.f, h3 = 0.f;                       \
      _Pragma("unroll")                                                   \
      for (int k = 0; k < 16; ++k) {                                      \
          const float xd = xs[buf][wave][(lane >> 2) + 16 * k];           \
          h0 += xd * a[k][0]; h1 += xd * a[k][1];                         \
          h2 += xd * a[k][2]; h3 += xd * a[k][3];                         \
      }                                                                   \
      _Pragma("unroll")                                                   \
      for (int off = 4; off <= 32; off <<= 1) {                           \
          h0 += __shfl_xor(h0, off, 64); h1 += __shfl_xor(h1, off, 64);   \
          h2 += __shfl_xor(h2, off, 64); h3 += __shfl_xor(h3, off, 64);   \
      }                                                                   \
      if (lane < 4) {                                                     \
          hws[i][wave][4 * lane + 0] = h0;                                \
          hws[i][wave][4 * lane + 1] = h1;                                \
          hws[i][wave][4 * lane + 2] = h2;                                \
          hws[i][wave][4 * lane + 3] = h3;                                \
      } }

    // ---- phase 1: h[i][r] = x[xid_i] . A, 2-deep pipelined, LDS-staged ----
    float4v xv1;
    *(float4v*)(&xs[0][wave][4 * lane]) = xv0;
    for (int i = 0; i < n; i += 2) {
        if (i + 1 < n)
            xv1 = *(const float4v*)(x + (size_t)xidl[i + 1] * D + xcol);
        ROW_COMPUTE(i, 0);
        if (i + 1 < n) {
            *(float4v*)(&xs[1][wave][4 * lane]) = xv1;
            if (i + 2 < n)
                xv0 = *(const float4v*)(x + (size_t)xidl[i + 2] * D + xcol);
            ROW_COMPUTE(i + 1, 1);
            if (i + 2 < n)
                *(float4v*)(&xs[0][wave][4 * lane]) = xv0;
        }
    }
#undef ROW_COMPUTE

    // B loads issued before the barrier: fetch overlaps hl-combine; a[] is
    // dead here so these reuse its registers.
    const float* Bw = B + (size_t)w * R * D + 4 * t;
    float4v breg[R];
    #pragma unroll
    for (int r = 0; r < R; ++r) breg[r] = *(const float4v*)(Bw + (size_t)r * D);

    __syncthreads();
    for (int idx = t; idx < n * R; idx += 1024) {
        const int i = idx >> 4, r = idx & 15;
        float sacc = 0.f;
        #pragma unroll
        for (int j = 0; j < NWAVE; ++j) sacc += hws[i][j][r];
        hl[i][r] = sacc;
    }
    __syncthreads();

    // ---- phase 2: y = 2*h.B ----
    for (int i = 0; i < n; ++i) {
        const int b = list[i];
        float4v acc = {0.f, 0.f, 0.f, 0.f};
        #pragma unroll
        for (int r = 0; r < R; ++r) {
            const float hr = hl[i][r];         // LDS broadcast
            acc[0] += hr * breg[r][0];
            acc[1] += hr * breg[r][1];
            acc[2] += hr * breg[r][2];
            acc[3] += hr * breg[r][3];
        }
        #pragma unroll
        for (int k = 0; k < 4; ++k) acc[k] *= 2.0f;

        if (b < NBL * 4) {
            *(float4v*)(ybuf + (size_t)b * D + 4 * t) = acc;        // unique writer
        } else {
            *(float4v*)(out + (size_t)(NBL + (b - NBL * 4)) * D + 4 * t) = acc;
        }
    }
}

// ---------------- sum4: out[o] = ybuf[4o]+ybuf[4o+1]+ybuf[4o+2]+ybuf[4o+3] ---
__global__ __launch_bounds__(256) void sum4_kernel(
    const float* __restrict__ ybuf,
    float* __restrict__ out)
{
    const int o = blockIdx.x >> 2;            // 0..255
    const int q = blockIdx.x & 3;             // d-quarter
    const int col = q * 1024 + 4 * threadIdx.x;
    const float* y0 = ybuf + (size_t)(4 * o) * D + col;
    float4v v0 = *(const float4v*)(y0);
    float4v v1 = *(const float4v*)(y0 + D);
    float4v v2 = *(const float4v*)(y0 + 2 * D);
    float4v v3 = *(const float4v*)(y0 + 3 * D);
    float4v s;
    #pragma unroll
    for (int k = 0; k < 4; ++k) s[k] = (v0[k] + v1[k]) + (v2[k] + v3[k]);
    *(float4v*)(out + (size_t)o * D + col) = s;
}

extern "C" void kernel_launch(void* const* d_in, const int* in_sizes, int n_in,
                              void* d_out, int out_size, void* d_ws, size_t ws_size,
                              hipStream_t stream) {
    const float* x    = (const float*)d_in[0];
    const float* A    = (const float*)d_in[1];
    const float* B    = (const float*)d_in[2];
    const int*   xids = (const int*)d_in[3];
    const int*   wids = (const int*)d_in[4];
    float*       out  = (float*)d_out;

    float* ybuf = (float*)d_ws;   // [1024][4096] f32 = 16 MB

    hipLaunchKernelGGL(fused_kernel, dim3(NW), dim3(1024), 0, stream,
                       x, A, B, xids, wids, ybuf, out);
    hipLaunchKernelGGL(sum4_kernel, dim3(NBL * 4), dim3(256), 0, stream,
                       ybuf, out);
}